// Round 2
// baseline (1228.768 us; speedup 1.0000x reference)
//
#include <hip/hip_runtime.h>
#include <math.h>

#define NU 50000
#define NUS 20000
#define NI 100000
#define NIS 20000
#define E_US 200000
#define E_IS 400000
#define E_UI 500000
#define BQ 1024
#define NT 240000                        // NUS+NU+NIS+NI+NU dst nodes over 5 edge sets
#define EPOOL (2 * E_US + 2 * E_IS + E_UI)

static __device__ __forceinline__ float4 f4zero() { return make_float4(0.f, 0.f, 0.f, 0.f); }

static __device__ __forceinline__ void fma4(float4& acc, float s, const float4& w) {
  acc.x = fmaf(s, w.x, acc.x);
  acc.y = fmaf(s, w.y, acc.y);
  acc.z = fmaf(s, w.z, acc.z);
  acc.w = fmaf(s, w.w, acc.w);
}

// ---------------- fused embedding gather: 4 tables of [*,64] f32 ----------------
__global__ void gather_all(const float* __restrict__ t0, const int* __restrict__ id0,
                           float* __restrict__ o0, int n0, const float* __restrict__ t1,
                           const int* __restrict__ id1, float* __restrict__ o1, int n1,
                           const float* __restrict__ t2, const int* __restrict__ id2,
                           float* __restrict__ o2, int n2, const float* __restrict__ t3,
                           const int* __restrict__ id3, float* __restrict__ o3, int n3) {
  int y = blockIdx.y;
  const float* t;
  const int* id;
  float* o;
  int n;
  if (y == 0) { t = t0; id = id0; o = o0; n = n0; }
  else if (y == 1) { t = t1; id = id1; o = o1; n = n1; }
  else if (y == 2) { t = t2; id = id2; o = o2; n = n2; }
  else { t = t3; id = id3; o = o3; n = n3; }
  int i = blockIdx.x * blockDim.x + threadIdx.x;  // over n*16 float4s
  if (i >= n * 16) return;
  int row = i >> 4, j = i & 15;
  ((float4*)o)[i] = ((const float4*)(t + (size_t)id[row] * 64))[j];
}

// ---------------- CSR build over all 5 edge sets at once ----------------
struct EdgeSets {
  const int* es[5];
  const int* ed[5];
  int E[5];
  int base[5];
};

__global__ void zero_ints(int* __restrict__ p, int n) {
  int i = blockIdx.x * blockDim.x + threadIdx.x;
  if (i < n) p[i] = 0;
}

__global__ void hist5(EdgeSets S, int* __restrict__ cnt) {
  int y = blockIdx.y;
  int e = blockIdx.x * blockDim.x + threadIdx.x;
  if (e < S.E[y]) atomicAdd(&cnt[S.base[y] + S.ed[y][e]], 1);
}

// scan-free region allocation: wave-level inclusive scan + one atomic per wave
__global__ void alloc_offsets(const int* __restrict__ cnt, int* __restrict__ start,
                              int* __restrict__ wo, int* __restrict__ cursor, int n) {
  int i = blockIdx.x * blockDim.x + threadIdx.x;
  int lane = threadIdx.x & 63;
  int c = (i < n) ? cnt[i] : 0;
  int s = c;
#pragma unroll
  for (int o = 1; o < 64; o <<= 1) {
    int y = __shfl_up(s, o);
    if (lane >= o) s += y;
  }
  int base = 0;
  if (lane == 63) base = atomicAdd(cursor, s);
  base = __shfl(base, 63);
  if (i < n) {
    int st = base + s - c;
    start[i] = st;
    wo[i] = st;
  }
}

__global__ void scatter5(EdgeSets S, int* __restrict__ wo, int* __restrict__ srcp) {
  int y = blockIdx.y;
  int e = blockIdx.x * blockDim.x + threadIdx.x;
  if (e < S.E[y]) {
    int p = atomicAdd(&wo[S.base[y] + S.ed[y][e]], 1);
    srcp[p] = S.es[y][e];
  }
}

// ---------------- fp32 GEMM with optional concat input + fused attention logits ----
// C[N,Kout] = [A1 | A2] @ W ; logits[n,h] = dot(C[n, h*fo:(h+1)*fo], avec[h])
// 32-row x 128-col tile per block, 4x4 register blocking, per-chunk W staging (20.6KB LDS).
__global__ __launch_bounds__(256, 2) void gemm_fused(
    const float* __restrict__ A1, int K1, const float* __restrict__ A2, int K2,
    const float* __restrict__ W, int Kout, const float* __restrict__ avec,
    float* __restrict__ logits, int fo_shift, float* __restrict__ C, int N) {
  __shared__ float Wlds[32 * 128];
  __shared__ float Alds[32 * 36];  // [k][r] transposed, stride 36 (16B-aligned, conflict-free)
  const int t = threadIdx.x;
  const int cbase = blockIdx.y * 128;
  const int colpos = t & 31;
  const int c0 = colpos << 2;      // 4 cols
  const int rg = (t >> 5) << 2;    // 4 rows
  const int sr = t >> 3;           // staging row 0..31
  const int sk = (t & 7) << 2;     // staging k-offset
  const int rt = blockIdx.x * 32;
  const int KT = K1 + K2;

  float4 acc[4] = {f4zero(), f4zero(), f4zero(), f4zero()};
  for (int kc = 0; kc < KT; kc += 32) {
    __syncthreads();
    for (int i = t; i < 1024; i += 256) {  // W chunk: 32k x 128c = 1024 float4s
      int k = i >> 5, c4 = (i & 31) << 2;
      *(float4*)&Wlds[k * 128 + c4] = *(const float4*)&W[(size_t)(kc + k) * Kout + cbase + c4];
    }
    {
      int row = rt + sr;
      float4 v = f4zero();
      if (row < N) {
        if (kc < K1) v = *(const float4*)&A1[(size_t)row * K1 + kc + sk];
        else v = *(const float4*)&A2[(size_t)row * K2 + (kc - K1) + sk];
      }
      Alds[(sk + 0) * 36 + sr] = v.x;
      Alds[(sk + 1) * 36 + sr] = v.y;
      Alds[(sk + 2) * 36 + sr] = v.z;
      Alds[(sk + 3) * 36 + sr] = v.w;
    }
    __syncthreads();
#pragma unroll
    for (int k = 0; k < 32; ++k) {
      float4 w = *(float4*)&Wlds[k * 128 + c0];
      float4 a = *(float4*)&Alds[k * 36 + rg];
      fma4(acc[0], a.x, w);
      fma4(acc[1], a.y, w);
      fma4(acc[2], a.z, w);
      fma4(acc[3], a.w, w);
    }
  }
  if (C) {
#pragma unroll
    for (int ri = 0; ri < 4; ++ri) {
      int row = rt + rg + ri;
      if (row < N) *(float4*)&C[(size_t)row * Kout + cbase + c0] = acc[ri];
    }
  }
  if (avec) {
    float4 av = *(const float4*)&avec[cbase + c0];
    const int gsz = 1 << (fo_shift - 2);  // col-lanes per head (8 for fo=32, 16 for fo=64)
    const int h = (cbase + c0) >> fo_shift;
    float part[4];
#pragma unroll
    for (int ri = 0; ri < 4; ++ri)
      part[ri] = acc[ri].x * av.x + acc[ri].y * av.y + acc[ri].z * av.z + acc[ri].w * av.w;
    for (int off = 1; off < gsz; off <<= 1) {
#pragma unroll
      for (int ri = 0; ri < 4; ++ri) part[ri] += __shfl_xor(part[ri], off);
    }
    if ((colpos & (gsz - 1)) == 0) {
#pragma unroll
      for (int ri = 0; ri < 4; ++ri) {
        int row = rt + rg + ri;
        if (row < N) logits[(size_t)row * 4 + h] = part[ri];
      }
    }
  }
}

// ---------------- GAT aggregation: one wave per dst node; exp recomputed in-register ----
// out[n,f] = (sum_e x_e * fs[src_e, f]) / max(sum_e x_e, 1e-12) + bias[f]
// x_e = exp(leakyrelu(el[src_e,h] + er[n,h], 0.2));  max-shift skipped (|e| << 1).
template <int NF>  // floats per lane; K = NF*64; head = lane>>4 holds for K=128 and 256
__global__ __launch_bounds__(256) void gat_aggregate(
    const float* __restrict__ fs, const float* __restrict__ el, const float* __restrict__ er,
    const int* __restrict__ srcp, const int* __restrict__ start, const int* __restrict__ cnt,
    const float* __restrict__ bias, float* __restrict__ out, int Nd, int nodeBase) {
  int node = (blockIdx.x * 256 + threadIdx.x) >> 6;
  if (node >= Nd) return;
  int lane = threadIdx.x & 63;
  constexpr int K = NF * 64;
  int h = lane >> 4;
  int f0 = lane * NF;
  float acc[NF] = {};
  float den = 0.f;
  float erh = er[(size_t)node * 4 + h];
  int s = start[nodeBase + node];
  int e1 = s + cnt[nodeBase + node];
  for (int p = s; p < e1; ++p) {
    int src = srcp[p];
    float z = el[(size_t)src * 4 + h] + erh;
    float x = expf(z > 0.f ? z : 0.2f * z);
    const float* fr = fs + (size_t)src * K + f0;
    if (NF == 2) {
      float2 v = *(const float2*)fr;
      acc[0] = fmaf(x, v.x, acc[0]);
      acc[1] = fmaf(x, v.y, acc[1]);
    } else {
      float4 v = *(const float4*)fr;
      acc[0] = fmaf(x, v.x, acc[0]);
      acc[1] = fmaf(x, v.y, acc[1]);
      acc[2] = fmaf(x, v.z, acc[2]);
      acc[3] = fmaf(x, v.w, acc[3]);
    }
    den += x;
  }
  float inv = 1.f / fmaxf(den, 1e-12f);
#pragma unroll
  for (int j = 0; j < NF; ++j)
    out[(size_t)node * K + f0 + j] = fmaf(acc[j], inv, bias[f0 + j]);
}

// ---------------- final: out = relu(h5[idx] @ Wm + bm), one wave per output row ----------------
__global__ void final_mlp(const float* __restrict__ h5, const int* __restrict__ idx,
                          const float* __restrict__ Wm, const float* __restrict__ bm,
                          float* __restrict__ out, int Bn) {
  int wave = (blockIdx.x * 256 + threadIdx.x) >> 6;
  int lane = threadIdx.x & 63;
  if (wave >= Bn) return;
  const float* row = h5 + (size_t)idx[wave] * 256;
  float acc = bm[lane];
  for (int k = 0; k < 256; ++k) acc = fmaf(row[k], Wm[k * 64 + lane], acc);
  out[wave * 64 + lane] = fmaxf(acc, 0.f);
}

static inline int cdiv(int a, int b) { return (a + b - 1) / b; }

extern "C" void kernel_launch(void* const* d_in, const int* in_sizes, int n_in, void* d_out,
                              int out_size, void* d_ws, size_t ws_size, hipStream_t stream) {
  const int* user_ids = (const int*)d_in[0];
  const int* usem_ids = (const int*)d_in[1];
  const int* item_ids = (const int*)d_in[2];
  const int* isem_ids = (const int*)d_in[3];
  const int* us_src = (const int*)d_in[4];
  const int* us_dst = (const int*)d_in[5];
  const int* is_src = (const int*)d_in[6];
  const int* is_dst = (const int*)d_in[7];
  const int* ui_src = (const int*)d_in[8];
  const int* ui_dst = (const int*)d_in[9];
  const int* user_out_idx = (const int*)d_in[10];
  const float* user_table = (const float*)d_in[11];
  const float* usem_table = (const float*)d_in[12];
  const float* item_table = (const float*)d_in[13];
  const float* isem_table = (const float*)d_in[14];
  const float* R[5][5];  // {Wsrc, Wdst, al, ar, b} for r1..r5
  for (int r = 0; r < 5; ++r)
    for (int j = 0; j < 5; ++j) R[r][j] = (const float*)d_in[15 + r * 5 + j];
  const float* Wm = (const float*)d_in[40];
  const float* bm = (const float*)d_in[41];
  float* out = (float*)d_out;

  // workspace bump allocator (16B aligned)
  float* ws = (float*)d_ws;
  size_t off = 0;
  auto alloc = [&](size_t n) {
    float* p = ws + off;
    off += (n + 3) & ~(size_t)3;
    return p;
  };
  float* user_emb = alloc((size_t)NU * 64);
  float* u_quant = alloc((size_t)NUS * 64);
  float* item_emb = alloc((size_t)NI * 64);
  float* i_quant = alloc((size_t)NIS * 64);
  float* u_n = alloc((size_t)NUS * 128);
  float* u_h = alloc((size_t)NU * 128);
  float* i_n = alloc((size_t)NIS * 128);
  float* i_h = alloc((size_t)NI * 128);
  float* h5 = alloc((size_t)NU * 256);
  float* fsb = alloc((size_t)NI * 256);
  float* elb = alloc((size_t)NI * 4);
  float* erb = alloc((size_t)NI * 4);
  int* cnt = (int*)alloc(NT + 4);      // +1 cursor at cnt[NT]
  int* startb = (int*)alloc(NT + 4);
  int* wob = (int*)alloc(NT + 4);
  int* srcp = (int*)alloc(EPOOL);

  // ---- CSR build for all 5 relations (edge lists are inputs; independent of GEMMs) ----
  // bases: r1(dst=NUS):0  r4(dst=NU):20000  r2(dst=NIS):70000  r3(dst=NI):90000  r5(dst=NU):190000
  EdgeSets S;
  S.es[0] = us_src; S.ed[0] = us_dst; S.E[0] = E_US; S.base[0] = 0;
  S.es[1] = us_dst; S.ed[1] = us_src; S.E[1] = E_US; S.base[1] = NUS;
  S.es[2] = is_src; S.ed[2] = is_dst; S.E[2] = E_IS; S.base[2] = NUS + NU;
  S.es[3] = is_dst; S.ed[3] = is_src; S.E[3] = E_IS; S.base[3] = NUS + NU + NIS;
  S.es[4] = ui_src; S.ed[4] = ui_dst; S.E[4] = E_UI; S.base[4] = NUS + NU + NIS + NI;

  zero_ints<<<cdiv(NT + 1, 1024), 1024, 0, stream>>>(cnt, NT + 1);
  gather_all<<<dim3(cdiv(NI * 16, 256), 4), 256, 0, stream>>>(
      user_table, user_ids, user_emb, NU, usem_table, usem_ids, u_quant, NUS, item_table,
      item_ids, item_emb, NI, isem_table, isem_ids, i_quant, NIS);
  hist5<<<dim3(cdiv(E_UI, 256), 5), 256, 0, stream>>>(S, cnt);
  alloc_offsets<<<cdiv(NT, 256), 256, 0, stream>>>(cnt, startb, wob, cnt + NT, NT);
  scatter5<<<dim3(cdiv(E_UI, 256), 5), 256, 0, stream>>>(S, wob, srcp);

  auto gemm = [&](const float* A1, int K1, const float* A2, int K2, const float* W, int Kout,
                  const float* av, float* lg, int fo_shift, float* Cc, int N) {
    gemm_fused<<<dim3(cdiv(N, 32), Kout / 128), 256, 0, stream>>>(A1, K1, A2, K2, W, Kout, av,
                                                                  lg, fo_shift, Cc, N);
  };
  auto agg = [&](int Kout, float* outb, const float* bias, int Nd, int base) {
    if (Kout == 128)
      gat_aggregate<2><<<cdiv(Nd, 4), 256, 0, stream>>>(fsb, elb, erb, srcp, startb, cnt, bias,
                                                        outb, Nd, base);
    else
      gat_aggregate<4><<<cdiv(Nd, 4), 256, 0, stream>>>(fsb, elb, erb, srcp, startb, cnt, bias,
                                                        outb, Nd, base);
  };

  // r1: user -shares-> u_sem
  gemm(user_emb, 64, nullptr, 0, R[0][0], 128, R[0][2], elb, 5, fsb, NU);
  gemm(u_quant, 64, nullptr, 0, R[0][1], 128, R[0][3], erb, 5, nullptr, NUS);  // er only
  agg(128, u_n, R[0][4], NUS, 0);
  // r4: u_sem -denotes-> user, src feats = concat(u_n, u_quant)
  gemm(u_n, 128, u_quant, 64, R[3][0], 128, R[3][2], elb, 5, fsb, NUS);
  gemm(user_emb, 64, nullptr, 0, R[3][1], 128, R[3][3], erb, 5, nullptr, NU);
  agg(128, u_h, R[3][4], NU, NUS);
  // r2: item -shares-> i_sem
  gemm(item_emb, 64, nullptr, 0, R[1][0], 128, R[1][2], elb, 5, fsb, NI);
  gemm(i_quant, 64, nullptr, 0, R[1][1], 128, R[1][3], erb, 5, nullptr, NIS);
  agg(128, i_n, R[1][4], NIS, NUS + NU);
  // r3: i_sem -denotes-> item, src feats = concat(i_n, i_quant)
  gemm(i_n, 128, i_quant, 64, R[2][0], 128, R[2][2], elb, 5, fsb, NIS);
  gemm(item_emb, 64, nullptr, 0, R[2][1], 128, R[2][3], erb, 5, nullptr, NI);
  agg(128, i_h, R[2][4], NI, NUS + NU + NIS);
  // r5: item -clicked_by-> user
  gemm(i_h, 128, nullptr, 0, R[4][0], 256, R[4][2], elb, 6, fsb, NI);
  gemm(u_h, 128, nullptr, 0, R[4][1], 256, R[4][3], erb, 6, nullptr, NU);
  agg(256, h5, R[4][4], NU, NUS + NU + NIS + NI);

  // batch gather + user_gnn_mapping (Linear + ReLU)
  final_mlp<<<cdiv(BQ, 4), 256, 0, stream>>>(h5, user_out_idx, Wm, bm, out, BQ);
}

// Round 3
// 1063.293 us; speedup vs baseline: 1.1556x; 1.1556x over previous
//
#include <hip/hip_runtime.h>
#include <math.h>

#define NU 50000
#define NUS 20000
#define NI 100000
#define NIS 20000
#define E_US 200000
#define E_IS 400000
#define E_UI 500000
#define BQ 1024
#define NT 240000  // NUS+NU+NIS+NI+NU dst nodes over 5 edge sets
#define EPOOL (2 * E_US + 2 * E_IS + E_UI)

typedef __attribute__((ext_vector_type(8))) short short8v;  // 8 x bf16 (4 VGPR)
typedef __attribute__((ext_vector_type(4))) float f32x4;    // MFMA C/D frag

static __device__ __forceinline__ unsigned short f2b(float f) {  // RNE f32->bf16
  unsigned u = __float_as_uint(f);
  u = u + 0x7FFFu + ((u >> 16) & 1u);
  return (unsigned short)(u >> 16);
}
static __device__ __forceinline__ float b2f(unsigned short h) {
  return __uint_as_float(((unsigned)h) << 16);
}

// ---------------- prep: transpose Wsrc -> bf16 Wt[col][k]; war[k][h] = Wdst @ ar ----------------
struct PrepArgs {
  const float* Wsrc[5];
  const float* Wdst[5];
  const float* ar[5];
  unsigned short* Wt[5];
  float* war[5];
  int K[5], Kout[5], Kd[5], fo[5];
};
__global__ void prep_kernel(PrepArgs P) {
  int y = blockIdx.y;
  int t = blockIdx.x * blockDim.x + threadIdx.x;
  int nth = gridDim.x * blockDim.x;
  if (y < 5) {
    int K = P.K[y], Kout = P.Kout[y];
    for (int i = t; i < K * Kout; i += nth) {
      int c = i / K, k = i - c * K;
      P.Wt[y][(size_t)c * K + k] = f2b(P.Wsrc[y][(size_t)k * Kout + c]);
    }
  } else {
    for (int r = 0; r < 5; ++r) {
      int Kd = P.Kd[r], fo = P.fo[r];
      for (int i = t; i < Kd * 4; i += nth) {
        int k = i >> 2, h = i & 3;
        const float* wrow = P.Wdst[r] + (size_t)k * (4 * fo) + h * fo;
        const float* arow = P.ar[r] + h * fo;
        float s = 0.f;
        for (int c = 0; c < fo; ++c) s += wrow[c] * arow[c];
        P.war[r][i] = s;
      }
    }
  }
}

// ---------------- gather (f32 table -> bf16 rows) + fused er = x . war ----------------
struct GatherArgs {
  const float* tab[4];
  const int* ids[4];
  unsigned short* out[4];
  const float* war[4];  // [64][4]
  float* er[4];         // [n][4]
  int n[4];
};
__global__ __launch_bounds__(256) void gather_er(GatherArgs G) {
  int y = blockIdx.y;
  int wave = (blockIdx.x * 256 + threadIdx.x) >> 6;
  int lane = threadIdx.x & 63;
  if (wave >= G.n[y]) return;
  float x = G.tab[y][(size_t)G.ids[y][wave] * 64 + lane];
  G.out[y][(size_t)wave * 64 + lane] = f2b(x);
  const float* war = G.war[y] + lane * 4;
  float p0 = x * war[0], p1 = x * war[1], p2 = x * war[2], p3 = x * war[3];
#pragma unroll
  for (int off = 1; off < 64; off <<= 1) {
    p0 += __shfl_xor(p0, off);
    p1 += __shfl_xor(p1, off);
    p2 += __shfl_xor(p2, off);
    p3 += __shfl_xor(p3, off);
  }
  if (lane == 0) *(float4*)&G.er[y][(size_t)wave * 4] = make_float4(p0, p1, p2, p3);
}

// ---------------- CSR build over all 5 edge sets ----------------
struct EdgeSets {
  const int* es[5];
  const int* ed[5];
  int E[5];
  int base[5];
};
__global__ void zero_ints(int* __restrict__ p, int n) {
  int i = blockIdx.x * blockDim.x + threadIdx.x;
  if (i < n) p[i] = 0;
}
__global__ void hist5(EdgeSets S, int* __restrict__ cnt) {
  int y = blockIdx.y;
  int e = blockIdx.x * blockDim.x + threadIdx.x;
  if (e < S.E[y]) atomicAdd(&cnt[S.base[y] + S.ed[y][e]], 1);
}
__global__ void alloc_offsets(const int* __restrict__ cnt, int* __restrict__ start,
                              int* __restrict__ wo, int* __restrict__ cursor, int n) {
  int i = blockIdx.x * blockDim.x + threadIdx.x;
  int lane = threadIdx.x & 63;
  int c = (i < n) ? cnt[i] : 0;
  int s = c;
#pragma unroll
  for (int o = 1; o < 64; o <<= 1) {
    int y = __shfl_up(s, o);
    if (lane >= o) s += y;
  }
  int base = 0;
  if (lane == 63) base = atomicAdd(cursor, s);
  base = __shfl(base, 63);
  if (i < n) {
    start[i] = base + s - c;
    wo[i] = base + s - c;
  }
}
__global__ void scatter5(EdgeSets S, int* __restrict__ wo, int* __restrict__ srcp) {
  int y = blockIdx.y;
  int e = blockIdx.x * blockDim.x + threadIdx.x;
  if (e < S.E[y]) {
    int p = atomicAdd(&wo[S.base[y] + S.ed[y][e]], 1);
    srcp[p] = S.es[y][e];
  }
}

// ---------------- bf16 MFMA GEMM: C[N,Kout] = [A1|A2] @ W, + fused el logits ----------------
// Block 256 thr = 4 waves (2x2); tile 64 rows x 128 cols; wave-tile 32x64.
// Wt is W pre-transposed [Kout][KT] bf16. LDS tiles XOR-swizzled in 16B units (T2).
// MFMA v_mfma_f32_16x16x32_bf16: A row=lane&15,k=(lane>>4)*8+j; C col=lane&15,row=(lane>>4)*4+q.
template <int KT>
__global__ __launch_bounds__(256, 2) void gemm_mfma(
    const unsigned short* __restrict__ A1, int K1, const unsigned short* __restrict__ A2,
    const unsigned short* __restrict__ Wt, int Kout, const float* __restrict__ al,
    float* __restrict__ elb, int fo_shift, unsigned short* __restrict__ Cb, int N) {
  constexpr int KU = KT / 8;  // 16B units per row
  __shared__ unsigned short Alds[64 * KT];
  __shared__ unsigned short Wlds[128 * KT];
  const int t = threadIdx.x;
  const int lane = t & 63;
  const int wid = t >> 6;
  const int wr = wid >> 1, wc = wid & 1;
  const int cb = blockIdx.y * 128;
  const int lr = lane & 15;
  const int lkg = lane >> 4;  // k-group 0..3 (8 k's each)
  const int K2 = KT - K1;

  // stage W column-tile once per block (rows = output cols)
  for (int i = t; i < 128 * KU; i += 256) {
    int c = i / KU, u = i - c * KU;
    float4 v = *(const float4*)&Wt[(size_t)(cb + c) * KT + u * 8];
    *(float4*)&Wlds[c * KT + ((u ^ (c & 7)) << 3)] = v;
  }

  for (int rt = blockIdx.x * 64; rt < N; rt += gridDim.x * 64) {
    __syncthreads();  // protect Alds (prev iter readers) / make Wlds visible (first iter)
    for (int i = t; i < 64 * KU; i += 256) {
      int r = i / KU, u = i - r * KU;
      int row = rt + r;
      float4 v = make_float4(0.f, 0.f, 0.f, 0.f);
      if (row < N) {
        int kb = u * 8;
        const unsigned short* p =
            (kb < K1) ? (A1 + (size_t)row * K1 + kb) : (A2 + (size_t)row * K2 + (kb - K1));
        v = *(const float4*)p;
      }
      *(float4*)&Alds[r * KT + ((u ^ (r & 7)) << 3)] = v;
    }
    __syncthreads();

    f32x4 acc[2][4];
#pragma unroll
    for (int m = 0; m < 2; ++m)
#pragma unroll
      for (int n = 0; n < 4; ++n) acc[m][n] = (f32x4){0.f, 0.f, 0.f, 0.f};

#pragma unroll
    for (int kc = 0; kc < KT; kc += 32) {
      const int slot = (((kc >> 3) + lkg) ^ (lane & 7)) << 3;
      short8v a0 = *(const short8v*)&Alds[(wr * 32 + lr) * KT + slot];
      short8v a1 = *(const short8v*)&Alds[(wr * 32 + 16 + lr) * KT + slot];
#pragma unroll
      for (int n = 0; n < 4; ++n) {
        short8v b = *(const short8v*)&Wlds[(wc * 64 + n * 16 + lr) * KT + slot];
        acc[0][n] = __builtin_amdgcn_mfma_f32_16x16x32_bf16(a0, b, acc[0][n], 0, 0, 0);
        acc[1][n] = __builtin_amdgcn_mfma_f32_16x16x32_bf16(a1, b, acc[1][n], 0, 0, 0);
      }
    }

    // C store (bf16, scattered 2B)
    if (Cb) {
#pragma unroll
      for (int m = 0; m < 2; ++m)
#pragma unroll
        for (int q = 0; q < 4; ++q) {
          int row = rt + wr * 32 + m * 16 + lkg * 4 + q;
          if (row < N) {
#pragma unroll
            for (int n = 0; n < 4; ++n)
              Cb[(size_t)row * Kout + cb + wc * 64 + n * 16 + lr] = f2b(acc[m][n][q]);
          }
        }
    }
    // fused attention logits el[row][h] = dot(C row slice of head h, al[h])
    {
      float av[4];
#pragma unroll
      for (int n = 0; n < 4; ++n) av[n] = al[cb + wc * 64 + n * 16 + lr];
      const int npg = (1 << fo_shift) >> 4;  // n-frags per head (2 for fo=32, 4 for fo=64)
      const int hpw = 4 / npg;               // heads per wave tile
      for (int m = 0; m < 2; ++m)
        for (int g = 0; g < hpw; ++g) {
          float p[4] = {0.f, 0.f, 0.f, 0.f};
          for (int nn = 0; nn < npg; ++nn) {
            int n = g * npg + nn;
#pragma unroll
            for (int q = 0; q < 4; ++q) p[q] += acc[m][n][q] * av[n];
          }
#pragma unroll
          for (int off = 1; off < 16; off <<= 1) {
#pragma unroll
            for (int q = 0; q < 4; ++q) p[q] += __shfl_xor(p[q], off);
          }
          if (lr == 0) {
            int h = (cb + wc * 64 + (g << fo_shift)) >> fo_shift;
#pragma unroll
            for (int q = 0; q < 4; ++q) {
              int row = rt + wr * 32 + m * 16 + lkg * 4 + q;
              if (row < N) elb[(size_t)row * 4 + h] = p[q];
            }
          }
        }
    }
  }
}

// ---------------- GAT aggregation: one wave per dst node, bf16 fs, optional fused er5 ----------
template <int NF, bool ER5>  // NF bf16/lane; K = NF*64; head = lane>>4 for K=128,256
__global__ __launch_bounds__(256) void gat_agg(
    const unsigned short* __restrict__ fs, const float* __restrict__ el,
    const float* __restrict__ er, const int* __restrict__ srcp, const int* __restrict__ start,
    const int* __restrict__ cnt, const float* __restrict__ bias,
    unsigned short* __restrict__ outb, const float* __restrict__ war5, float* __restrict__ er5,
    int Nd, int nodeBase) {
  int node = (blockIdx.x * 256 + threadIdx.x) >> 6;
  if (node >= Nd) return;
  int lane = threadIdx.x & 63;
  constexpr int K = NF * 64;
  int h = lane >> 4;
  int f0 = lane * NF;
  float acc[NF] = {};
  float den = 0.f;
  float erh = er[(size_t)node * 4 + h];
  int s = start[nodeBase + node];
  int e1 = s + cnt[nodeBase + node];
  for (int p = s; p < e1; ++p) {
    int src = srcp[p];
    float z = el[(size_t)src * 4 + h] + erh;
    float x = expf(z > 0.f ? z : 0.2f * z);  // softmax max-shift skipped: |z| << 1
    const unsigned short* fr = fs + (size_t)src * K + f0;
    if (NF == 2) {
      unsigned v = *(const unsigned*)fr;
      acc[0] = fmaf(x, b2f((unsigned short)(v & 0xffff)), acc[0]);
      acc[1] = fmaf(x, b2f((unsigned short)(v >> 16)), acc[1]);
    } else {
      uint2 v = *(const uint2*)fr;
      acc[0] = fmaf(x, b2f((unsigned short)(v.x & 0xffff)), acc[0]);
      acc[1] = fmaf(x, b2f((unsigned short)(v.x >> 16)), acc[1]);
      acc[2] = fmaf(x, b2f((unsigned short)(v.y & 0xffff)), acc[2]);
      acc[3] = fmaf(x, b2f((unsigned short)(v.y >> 16)), acc[3]);
    }
    den += x;
  }
  float inv = 1.f / fmaxf(den, 1e-12f);
  float vout[NF];
#pragma unroll
  for (int j = 0; j < NF; ++j) vout[j] = fmaf(acc[j], inv, bias[f0 + j]);
  if (NF == 2) {
    unsigned pk = (unsigned)f2b(vout[0]) | ((unsigned)f2b(vout[1]) << 16);
    *(unsigned*)&outb[(size_t)node * K + f0] = pk;
  } else {
    uint2 pk;
    pk.x = (unsigned)f2b(vout[0]) | ((unsigned)f2b(vout[1]) << 16);
    pk.y = (unsigned)f2b(vout[2]) | ((unsigned)f2b(vout[3]) << 16);
    *(uint2*)&outb[(size_t)node * K + f0] = pk;
  }
  if (ER5) {  // er for r5 = u_h . war5 (f32, pre-round)
    float p0 = 0.f, p1 = 0.f, p2 = 0.f, p3 = 0.f;
#pragma unroll
    for (int j = 0; j < NF; ++j) {
      const float* wr = war5 + (size_t)(f0 + j) * 4;
      p0 += vout[j] * wr[0];
      p1 += vout[j] * wr[1];
      p2 += vout[j] * wr[2];
      p3 += vout[j] * wr[3];
    }
#pragma unroll
    for (int off = 1; off < 64; off <<= 1) {
      p0 += __shfl_xor(p0, off);
      p1 += __shfl_xor(p1, off);
      p2 += __shfl_xor(p2, off);
      p3 += __shfl_xor(p3, off);
    }
    if (lane == 0) *(float4*)&er5[(size_t)node * 4] = make_float4(p0, p1, p2, p3);
  }
}

// ---------------- final: out = relu(h5[idx] @ Wm + bm), one wave per output row ----------------
__global__ void final_mlp(const unsigned short* __restrict__ h5, const int* __restrict__ idx,
                          const float* __restrict__ Wm, const float* __restrict__ bm,
                          float* __restrict__ out, int Bn) {
  int wave = (blockIdx.x * 256 + threadIdx.x) >> 6;
  int lane = threadIdx.x & 63;
  if (wave >= Bn) return;
  const unsigned short* row = h5 + (size_t)idx[wave] * 256;
  float acc = bm[lane];
  for (int k = 0; k < 256; ++k) acc = fmaf(b2f(row[k]), Wm[k * 64 + lane], acc);
  out[wave * 64 + lane] = fmaxf(acc, 0.f);
}

static inline int cdiv(int a, int b) { return (a + b - 1) / b; }
static inline int imin(int a, int b) { return a < b ? a : b; }

extern "C" void kernel_launch(void* const* d_in, const int* in_sizes, int n_in, void* d_out,
                              int out_size, void* d_ws, size_t ws_size, hipStream_t stream) {
  const int* user_ids = (const int*)d_in[0];
  const int* usem_ids = (const int*)d_in[1];
  const int* item_ids = (const int*)d_in[2];
  const int* isem_ids = (const int*)d_in[3];
  const int* us_src = (const int*)d_in[4];
  const int* us_dst = (const int*)d_in[5];
  const int* is_src = (const int*)d_in[6];
  const int* is_dst = (const int*)d_in[7];
  const int* ui_src = (const int*)d_in[8];
  const int* ui_dst = (const int*)d_in[9];
  const int* user_out_idx = (const int*)d_in[10];
  const float* user_table = (const float*)d_in[11];
  const float* usem_table = (const float*)d_in[12];
  const float* item_table = (const float*)d_in[13];
  const float* isem_table = (const float*)d_in[14];
  const float* R[5][5];  // {Wsrc, Wdst, al, ar, b}
  for (int r = 0; r < 5; ++r)
    for (int j = 0; j < 5; ++j) R[r][j] = (const float*)d_in[15 + r * 5 + j];
  const float* Wm = (const float*)d_in[40];
  const float* bm = (const float*)d_in[41];
  float* out = (float*)d_out;

  // byte bump allocator, 256B aligned
  char* base = (char*)d_ws;
  size_t off = 0;
  auto alloc = [&](size_t bytes) {
    char* p = base + off;
    off += (bytes + 255) & ~(size_t)255;
    return p;
  };
  unsigned short* user_emb = (unsigned short*)alloc((size_t)NU * 64 * 2);
  unsigned short* u_quant = (unsigned short*)alloc((size_t)NUS * 64 * 2);
  unsigned short* item_emb = (unsigned short*)alloc((size_t)NI * 64 * 2);
  unsigned short* i_quant = (unsigned short*)alloc((size_t)NIS * 64 * 2);
  unsigned short* u_n = (unsigned short*)alloc((size_t)NUS * 128 * 2);
  unsigned short* u_h = (unsigned short*)alloc((size_t)NU * 128 * 2);
  unsigned short* i_n = (unsigned short*)alloc((size_t)NIS * 128 * 2);
  unsigned short* i_h = (unsigned short*)alloc((size_t)NI * 128 * 2);
  unsigned short* h5 = (unsigned short*)alloc((size_t)NU * 256 * 2);
  unsigned short* fsb = (unsigned short*)alloc((size_t)NI * 256 * 2);
  static const int WK[5] = {64, 64, 192, 192, 128};
  static const int WKOUT[5] = {128, 128, 128, 128, 256};
  static const int WKD[5] = {64, 64, 64, 64, 128};
  static const int WFO[5] = {32, 32, 32, 32, 64};
  unsigned short* Wt[5];
  float* war[5];
  for (int r = 0; r < 5; ++r) Wt[r] = (unsigned short*)alloc((size_t)WK[r] * WKOUT[r] * 2);
  for (int r = 0; r < 5; ++r) war[r] = (float*)alloc((size_t)WKD[r] * 4 * 4);
  float* elb = (float*)alloc((size_t)NI * 4 * 4);
  float* er1 = (float*)alloc((size_t)NUS * 4 * 4);
  float* er2 = (float*)alloc((size_t)NIS * 4 * 4);
  float* er3 = (float*)alloc((size_t)NI * 4 * 4);
  float* er4 = (float*)alloc((size_t)NU * 4 * 4);
  float* er5 = (float*)alloc((size_t)NU * 4 * 4);
  int* cnt = (int*)alloc((NT + 1) * 4);
  int* startb = (int*)alloc(NT * 4);
  int* wob = (int*)alloc(NT * 4);
  int* srcp = (int*)alloc((size_t)EPOOL * 4);

  // ---- prep (weights only) ----
  PrepArgs P;
  for (int r = 0; r < 5; ++r) {
    P.Wsrc[r] = R[r][0];
    P.Wdst[r] = R[r][1];
    P.ar[r] = R[r][3];
    P.Wt[r] = Wt[r];
    P.war[r] = war[r];
    P.K[r] = WK[r];
    P.Kout[r] = WKOUT[r];
    P.Kd[r] = WKD[r];
    P.fo[r] = WFO[r];
  }
  prep_kernel<<<dim3(32, 6), 256, 0, stream>>>(P);

  // ---- CSR build ----
  EdgeSets S;
  S.es[0] = us_src; S.ed[0] = us_dst; S.E[0] = E_US; S.base[0] = 0;                    // r1
  S.es[1] = us_dst; S.ed[1] = us_src; S.E[1] = E_US; S.base[1] = NUS;                  // r4
  S.es[2] = is_src; S.ed[2] = is_dst; S.E[2] = E_IS; S.base[2] = NUS + NU;             // r2
  S.es[3] = is_dst; S.ed[3] = is_src; S.E[3] = E_IS; S.base[3] = NUS + NU + NIS;       // r3
  S.es[4] = ui_src; S.ed[4] = ui_dst; S.E[4] = E_UI; S.base[4] = NUS + NU + NIS + NI;  // r5
  zero_ints<<<cdiv(NT + 1, 1024), 1024, 0, stream>>>(cnt, NT + 1);
  hist5<<<dim3(cdiv(E_UI, 256), 5), 256, 0, stream>>>(S, cnt);
  alloc_offsets<<<cdiv(NT, 256), 256, 0, stream>>>(cnt, startb, wob, cnt + NT, NT);
  scatter5<<<dim3(cdiv(E_UI, 256), 5), 256, 0, stream>>>(S, wob, srcp);

  // ---- gathers + fused er (r1..r4) ----
  GatherArgs G;
  G.tab[0] = user_table; G.ids[0] = user_ids; G.out[0] = user_emb; G.war[0] = war[3]; G.er[0] = er4; G.n[0] = NU;
  G.tab[1] = usem_table; G.ids[1] = usem_ids; G.out[1] = u_quant;  G.war[1] = war[0]; G.er[1] = er1; G.n[1] = NUS;
  G.tab[2] = item_table; G.ids[2] = item_ids; G.out[2] = item_emb; G.war[2] = war[2]; G.er[2] = er3; G.n[2] = NI;
  G.tab[3] = isem_table; G.ids[3] = isem_ids; G.out[3] = i_quant;  G.war[3] = war[1]; G.er[3] = er2; G.n[3] = NIS;
  gather_er<<<dim3(cdiv(NI, 4), 4), 256, 0, stream>>>(G);

  auto gemm = [&](int KT, const unsigned short* A1, int K1, const unsigned short* A2,
                  const unsigned short* Wtp, int Kout, const float* al, int fo_shift,
                  unsigned short* Cb, int N) {
    int gy = Kout / 128;
    dim3 g(imin(cdiv(N, 64), 768 / gy), gy);
    if (KT == 64)
      gemm_mfma<64><<<g, 256, 0, stream>>>(A1, K1, A2, Wtp, Kout, al, elb, fo_shift, Cb, N);
    else if (KT == 128)
      gemm_mfma<128><<<g, 256, 0, stream>>>(A1, K1, A2, Wtp, Kout, al, elb, fo_shift, Cb, N);
    else
      gemm_mfma<192><<<g, 256, 0, stream>>>(A1, K1, A2, Wtp, Kout, al, elb, fo_shift, Cb, N);
  };

  // r1: user -shares-> u_sem
  gemm(64, user_emb, 64, nullptr, Wt[0], 128, R[0][2], 5, fsb, NU);
  gat_agg<2, false><<<cdiv(NUS, 4), 256, 0, stream>>>(fsb, elb, er1, srcp, startb, cnt, R[0][4],
                                                      u_n, nullptr, nullptr, NUS, 0);
  // r4: u_sem -denotes-> user (reversed edges), src = concat(u_n, u_quant); fused er5 from u_h
  gemm(192, u_n, 128, u_quant, Wt[3], 128, R[3][2], 5, fsb, NUS);
  gat_agg<2, true><<<cdiv(NU, 4), 256, 0, stream>>>(fsb, elb, er4, srcp, startb, cnt, R[3][4],
                                                    u_h, war[4], er5, NU, NUS);
  // r2: item -shares-> i_sem
  gemm(64, item_emb, 64, nullptr, Wt[1], 128, R[1][2], 5, fsb, NI);
  gat_agg<2, false><<<cdiv(NIS, 4), 256, 0, stream>>>(fsb, elb, er2, srcp, startb, cnt, R[1][4],
                                                      i_n, nullptr, nullptr, NIS, NUS + NU);
  // r3: i_sem -denotes-> item, src = concat(i_n, i_quant)
  gemm(192, i_n, 128, i_quant, Wt[2], 128, R[2][2], 5, fsb, NIS);
  gat_agg<2, false><<<cdiv(NI, 4), 256, 0, stream>>>(fsb, elb, er3, srcp, startb, cnt, R[2][4],
                                                     i_h, nullptr, nullptr, NI, NUS + NU + NIS);
  // r5: item -clicked_by-> user
  gemm(128, i_h, 128, nullptr, Wt[4], 256, R[4][2], 6, fsb, NI);
  gat_agg<4, false><<<cdiv(NU, 4), 256, 0, stream>>>(fsb, elb, er5, srcp, startb, cnt, R[4][4],
                                                     h5, nullptr, nullptr, NU,
                                                     NUS + NU + NIS + NI);
  // batch gather + user_gnn_mapping
  final_mlp<<<cdiv(BQ, 4), 256, 0, stream>>>(h5, user_out_idx, Wm, bm, out, BQ);
}